// Round 1
// baseline (2656.925 us; speedup 1.0000x reference)
//
#include <hip/hip_runtime.h>
#include <cstdint>

#define B_ 4
#define C_ 128
#define K_ 64
#define H_ 256
#define W_ 256
#define HP 32
#define WP 32
#define L_ 1024
#define J_ 256
#define LC 64
#define NCH (L_ / LC)

// workspace layout (float offsets)
#define OFF_W1T1 0
#define OFF_W1T2 16384
#define OFF_W2T1 32768
#define OFF_W2T2 40960
#define OFF_WVT  49152
#define OFF_VLOG 65536
#define OFF_M1   (OFF_VLOG + J_ * K_ * L_)   // 16842752
#define OFF_M2   (OFF_M1 + J_ * C_ * K_)     // 18939904

__global__ void transpose_weights(const float* __restrict__ w1_1,
                                  const float* __restrict__ w1_2,
                                  const float* __restrict__ w2_1,
                                  const float* __restrict__ w2_2,
                                  const float* __restrict__ w_v,
                                  float* __restrict__ ws) {
    int tid = blockIdx.x * 256 + threadIdx.x;  // 0..65535
    if (tid < 16384) {
        int c = tid >> 7, o = tid & 127;
        ws[OFF_W1T1 + tid] = w1_1[o * 128 + c];
    } else if (tid < 32768) {
        int i = tid - 16384;
        int c = i >> 7, o = i & 127;
        ws[OFF_W1T2 + i] = w1_2[o * 128 + c];
    } else if (tid < 40960) {
        int i = tid - 32768;
        int c = i >> 6, k = i & 63;
        ws[OFF_W2T1 + i] = w2_1[k * 128 + c];
    } else if (tid < 49152) {
        int i = tid - 40960;
        int c = i >> 6, k = i & 63;
        ws[OFF_W2T2 + i] = w2_2[k * 128 + c];
    } else {
        int i = tid - 49152;
        int c = i >> 6, k = i & 63;   // c in [0,256)
        ws[OFF_WVT + i] = w_v[k * 256 + c];
    }
}

// One workgroup per j = b*64+q. Computes V logits -> ws, M1/M2 -> ws.
__global__ __launch_bounds__(512, 1) void proj_u_kernel(
    const float* __restrict__ x1, const float* __restrict__ x2,
    const float* __restrict__ b_v, const float* __restrict__ b1_1,
    const float* __restrict__ b2_1, const float* __restrict__ wout1,
    const float* __restrict__ b1_2, const float* __restrict__ b2_2,
    const float* __restrict__ wout2, float* __restrict__ ws) {
    __shared__ __align__(16) float Xs[C_ * LC];      // 8192 fl, 32KB
    __shared__ __align__(16) float Y1Ts[LC * 132];   // [dl][ch], pad 132 -> 33.8KB
    __shared__ __align__(16) float Y2Ts[LC * 68];    // [dl][k],  pad 68  -> 17.4KB

    const float* w1t1 = ws + OFF_W1T1;
    const float* w1t2 = ws + OFF_W1T2;
    const float* w2t1 = ws + OFF_W2T1;
    const float* w2t2 = ws + OFF_W2T2;
    const float* wvt  = ws + OFF_WVT;
    float* vlog = ws + OFF_VLOG;
    float* m1   = ws + OFF_M1;
    float* m2   = ws + OFF_M2;

    const int t = threadIdx.x;
    const int j = blockIdx.x;
    const int b = j >> 6, q = j & 63, i0 = q >> 3, i2 = q & 7;
    const int l = t & 63;
    const int gu = __builtin_amdgcn_readfirstlane(t >> 6);  // wave id 0..7

    const int ch0 = 4 * (t & 31);   // U-tile: 4 ch values
    const int k0  = 4 * (t >> 5);   // U-tile: 4 k values (t>>5 in [0,16))

    float U1[16], U2[16];
#pragma unroll
    for (int i = 0; i < 16; i++) { U1[i] = 0.f; U2[i] = 0.f; }

    const int imgbase = b * C_ * H_ * W_ + (i0 * HP) * W_ + i2 * WP;

    for (int lc = 0; lc < NCH; lc++) {
        float vacc[8];
#pragma unroll
        for (int i = 0; i < 8; i++) vacc[i] = b_v[gu * 8 + i];

        // ================= stream 1 =================
        __syncthreads();
#pragma unroll
        for (int r = 0; r < 4; r++) {
            int idx4 = r * 512 + t;            // 0..2047 float4s
            int c = idx4 >> 4, dl4 = idx4 & 15;
            int lg = lc * LC + dl4 * 4;
            int row = lg >> 5, col = lg & 31;
            float4 v = *(const float4*)(x1 + imgbase + c * (H_ * W_) + row * W_ + col);
            *(float4*)&Xs[idx4 * 4] = v;
        }
        __syncthreads();
        {   // projections for stream 1
            float a1[16], a2[8];
#pragma unroll
            for (int i = 0; i < 16; i++) a1[i] = b1_1[gu * 16 + i];
#pragma unroll
            for (int i = 0; i < 8; i++) a2[i] = b2_1[gu * 8 + i];
            for (int c = 0; c < C_; c++) {
                float xv = Xs[c * LC + l];
                const float* wr1 = w1t1 + c * 128 + gu * 16;
#pragma unroll
                for (int i = 0; i < 16; i++) a1[i] += wr1[i] * xv;
                const float* wr2 = w2t1 + c * 64 + gu * 8;
#pragma unroll
                for (int i = 0; i < 8; i++) a2[i] += wr2[i] * xv;
                const float* wrv = wvt + c * 64 + gu * 8;
#pragma unroll
                for (int i = 0; i < 8; i++) vacc[i] += wrv[i] * xv;
            }
#pragma unroll
            for (int i = 0; i < 16; i++) Y1Ts[l * 132 + gu * 16 + i] = a1[i];
#pragma unroll
            for (int i = 0; i < 8; i++) Y2Ts[l * 68 + gu * 8 + i] = a2[i];
        }
        __syncthreads();
        for (int dl = 0; dl < LC; dl++) {   // U1 += Y1 * Y2^T
            float4 av = *(const float4*)&Y1Ts[dl * 132 + ch0];
            float4 bv = *(const float4*)&Y2Ts[dl * 68 + k0];
            float ax[4] = {av.x, av.y, av.z, av.w};
            float bx[4] = {bv.x, bv.y, bv.z, bv.w};
#pragma unroll
            for (int ci = 0; ci < 4; ci++)
#pragma unroll
                for (int ki = 0; ki < 4; ki++) U1[ci * 4 + ki] += ax[ci] * bx[ki];
        }
        // ================= stream 2 =================
        __syncthreads();
#pragma unroll
        for (int r = 0; r < 4; r++) {
            int idx4 = r * 512 + t;
            int c = idx4 >> 4, dl4 = idx4 & 15;
            int lg = lc * LC + dl4 * 4;
            int row = lg >> 5, col = lg & 31;
            float4 v = *(const float4*)(x2 + imgbase + c * (H_ * W_) + row * W_ + col);
            *(float4*)&Xs[idx4 * 4] = v;
        }
        __syncthreads();
        {   // projections for stream 2 (+ finish V logits, write out)
            float a1[16], a2[8];
#pragma unroll
            for (int i = 0; i < 16; i++) a1[i] = b1_2[gu * 16 + i];
#pragma unroll
            for (int i = 0; i < 8; i++) a2[i] = b2_2[gu * 8 + i];
            for (int c = 0; c < C_; c++) {
                float xv = Xs[c * LC + l];
                const float* wr1 = w1t2 + c * 128 + gu * 16;
#pragma unroll
                for (int i = 0; i < 16; i++) a1[i] += wr1[i] * xv;
                const float* wr2 = w2t2 + c * 64 + gu * 8;
#pragma unroll
                for (int i = 0; i < 8; i++) a2[i] += wr2[i] * xv;
                const float* wrv = wvt + (128 + c) * 64 + gu * 8;
#pragma unroll
                for (int i = 0; i < 8; i++) vacc[i] += wrv[i] * xv;
            }
#pragma unroll
            for (int i = 0; i < 16; i++) Y1Ts[l * 132 + gu * 16 + i] = a1[i];
#pragma unroll
            for (int i = 0; i < 8; i++) Y2Ts[l * 68 + gu * 8 + i] = a2[i];
#pragma unroll
            for (int i = 0; i < 8; i++)
                vlog[j * (K_ * L_) + (gu * 8 + i) * L_ + lc * LC + l] = vacc[i];
        }
        __syncthreads();
        for (int dl = 0; dl < LC; dl++) {   // U2 += Y1 * Y2^T
            float4 av = *(const float4*)&Y1Ts[dl * 132 + ch0];
            float4 bv = *(const float4*)&Y2Ts[dl * 68 + k0];
            float ax[4] = {av.x, av.y, av.z, av.w};
            float bx[4] = {bv.x, bv.y, bv.z, bv.w};
#pragma unroll
            for (int ci = 0; ci < 4; ci++)
#pragma unroll
                for (int ki = 0; ki < 4; ki++) U2[ci * 4 + ki] += ax[ci] * bx[ki];
        }
    }

    // ================= epilogue: l2norm + M = Wout @ Un =================
    __syncthreads();
    {
        float ssq1[4], ssq2[4];
#pragma unroll
        for (int ki = 0; ki < 4; ki++) {
            float s1 = 0.f, s2 = 0.f;
#pragma unroll
            for (int ci = 0; ci < 4; ci++) {
                s1 += U1[ci * 4 + ki] * U1[ci * 4 + ki];
                s2 += U2[ci * 4 + ki] * U2[ci * 4 + ki];
            }
            ssq1[ki] = s1; ssq2[ki] = s2;
        }
        // reduce over the 32 lanes sharing this k-tile (consecutive half-wave)
#pragma unroll
        for (int off = 1; off < 32; off <<= 1) {
#pragma unroll
            for (int ki = 0; ki < 4; ki++) {
                ssq1[ki] += __shfl_xor(ssq1[ki], off, 64);
                ssq2[ki] += __shfl_xor(ssq2[ki], off, 64);
            }
        }
        float rn1[4], rn2[4];
#pragma unroll
        for (int ki = 0; ki < 4; ki++) {
            rn1[ki] = 1.f / (1e-6f + sqrtf(ssq1[ki]));
            rn2[ki] = 1.f / (1e-6f + sqrtf(ssq2[ki]));
        }
        // normalized U -> LDS (reuse Xs for Un1, Y1Ts for Un2), layout [ch][k]
#pragma unroll
        for (int ci = 0; ci < 4; ci++)
#pragma unroll
            for (int ki = 0; ki < 4; ki++) {
                Xs[(ch0 + ci) * 64 + (k0 + ki)]   = U1[ci * 4 + ki] * rn1[ki];
                Y1Ts[(ch0 + ci) * 64 + (k0 + ki)] = U2[ci * 4 + ki] * rn2[ki];
            }
    }
    __syncthreads();
    {
        const int kk = t & 63;
        float mc1[16], mc2[16];
#pragma unroll
        for (int i = 0; i < 16; i++) { mc1[i] = 0.f; mc2[i] = 0.f; }
        for (int c = 0; c < C_; c++) {
            float u1 = Xs[c * 64 + kk];
            float u2 = Y1Ts[c * 64 + kk];
#pragma unroll
            for (int i = 0; i < 16; i++) {
                mc1[i] += wout1[(gu * 16 + i) * 128 + c] * u1;
                mc2[i] += wout2[(gu * 16 + i) * 128 + c] * u2;
            }
        }
#pragma unroll
        for (int i = 0; i < 16; i++) {
            m1[j * 8192 + (gu * 16 + i) * 64 + kk] = mc1[i];
            m2[j * 8192 + (gu * 16 + i) * 64 + kk] = mc2[i];
        }
    }
}

// softmax(V) and out_s = M_s @ V, scattered back to image layout
__global__ __launch_bounds__(512, 1) void out_kernel(const float* __restrict__ ws,
                                                     float* __restrict__ out) {
    __shared__ __align__(16) float Vs[K_ * 256];   // 64KB
    __shared__ __align__(16) float Ms1[C_ * K_];   // 32KB
    __shared__ __align__(16) float Ms2[C_ * K_];   // 32KB

    const int t = threadIdx.x;
    const int bx = blockIdx.x;          // 0..1023
    const int j = bx >> 2, lcid = bx & 3;
    const int b = j >> 6, q = j & 63, i0 = q >> 3, i2 = q & 7;
    const int lbase = lcid * 256;
    const float* vlog = ws + OFF_VLOG + j * (K_ * L_);
    const float* m1 = ws + OFF_M1 + j * 8192;
    const float* m2 = ws + OFF_M2 + j * 8192;

#pragma unroll
    for (int r = 0; r < 4; r++) {
        int i4 = r * 512 + t;   // 2048 float4 = 8192 floats
        *(float4*)&Ms1[i4 * 4] = *(const float4*)(m1 + i4 * 4);
        *(float4*)&Ms2[i4 * 4] = *(const float4*)(m2 + i4 * 4);
    }
#pragma unroll
    for (int r = 0; r < 8; r++) {
        int i4 = r * 512 + t;   // 4096 float4 = 16384 floats
        int k = i4 >> 6, d4 = i4 & 63;
        *(float4*)&Vs[i4 * 4] = *(const float4*)(vlog + k * L_ + lbase + d4 * 4);
    }
    __syncthreads();
    if (t < 256) {   // softmax over k for each of the 256 columns
        int lcol = t;
        float mx = -1e30f;
        for (int k = 0; k < 64; k++) mx = fmaxf(mx, Vs[k * 256 + lcol]);
        float s = 0.f;
        for (int k = 0; k < 64; k++) {
            float e = __expf(Vs[k * 256 + lcol] - mx);
            Vs[k * 256 + lcol] = e;
            s += e;
        }
        float rs = 1.f / s;
        for (int k = 0; k < 64; k++) Vs[k * 256 + lcol] *= rs;
    }
    __syncthreads();

    const int dl = t & 255, og = t >> 8;  // og in {0,1}, wave-uniform
    const int lg = lbase + dl;
    const int i1 = lg >> 5, i3 = lg & 31;
    const int obase0 = b * C_ * H_ * W_ + (i0 * HP + i1) * W_ + i2 * WP + i3;
    float* out1 = out;
    float* out2 = out + B_ * C_ * H_ * W_;

    for (int ob = 0; ob < 4; ob++) {
        int o0 = og * 64 + ob * 16;
        float acc1[16], acc2[16];
#pragma unroll
        for (int i = 0; i < 16; i++) { acc1[i] = 0.f; acc2[i] = 0.f; }
        for (int kb = 0; kb < 16; kb++) {
            float v0 = Vs[(kb * 4 + 0) * 256 + dl];
            float v1 = Vs[(kb * 4 + 1) * 256 + dl];
            float v2 = Vs[(kb * 4 + 2) * 256 + dl];
            float v3 = Vs[(kb * 4 + 3) * 256 + dl];
#pragma unroll
            for (int i = 0; i < 16; i++) {
                float4 mr1 = *(const float4*)&Ms1[(o0 + i) * 64 + kb * 4];
                acc1[i] += mr1.x * v0 + mr1.y * v1 + mr1.z * v2 + mr1.w * v3;
                float4 mr2 = *(const float4*)&Ms2[(o0 + i) * 64 + kb * 4];
                acc2[i] += mr2.x * v0 + mr2.y * v1 + mr2.z * v2 + mr2.w * v3;
            }
        }
#pragma unroll
        for (int i = 0; i < 16; i++) {
            out1[obase0 + (o0 + i) * H_ * W_] = acc1[i];
            out2[obase0 + (o0 + i) * H_ * W_] = acc2[i];
        }
    }
}

extern "C" void kernel_launch(void* const* d_in, const int* in_sizes, int n_in,
                              void* d_out, int out_size, void* d_ws, size_t ws_size,
                              hipStream_t stream) {
    (void)in_sizes; (void)n_in; (void)out_size; (void)ws_size;
    const float* x1    = (const float*)d_in[0];
    const float* x2    = (const float*)d_in[1];
    const float* w_v   = (const float*)d_in[2];
    const float* b_v   = (const float*)d_in[3];
    const float* w1_1  = (const float*)d_in[4];
    const float* b1_1  = (const float*)d_in[5];
    const float* w2_1  = (const float*)d_in[6];
    const float* b2_1  = (const float*)d_in[7];
    const float* wout1 = (const float*)d_in[8];
    const float* w1_2  = (const float*)d_in[9];
    const float* b1_2  = (const float*)d_in[10];
    const float* w2_2  = (const float*)d_in[11];
    const float* b2_2  = (const float*)d_in[12];
    const float* wout2 = (const float*)d_in[13];
    float* ws  = (float*)d_ws;
    float* out = (float*)d_out;

    hipLaunchKernelGGL(transpose_weights, dim3(256), dim3(256), 0, stream,
                       w1_1, w1_2, w2_1, w2_2, w_v, ws);
    hipLaunchKernelGGL(proj_u_kernel, dim3(J_), dim3(512), 0, stream,
                       x1, x2, b_v, b1_1, b2_1, wout1, b1_2, b2_2, wout2, ws);
    hipLaunchKernelGGL(out_kernel, dim3(J_ * 4), dim3(512), 0, stream, ws, out);
}

// Round 2
// 946.161 us; speedup vs baseline: 2.8081x; 2.8081x over previous
//
#include <hip/hip_runtime.h>
#include <cstdint>

typedef __attribute__((ext_vector_type(8))) short short8;
typedef __attribute__((ext_vector_type(4))) float v4f;

#define B_ 4
#define C_ 128
#define K_ 64
#define H_ 256
#define W_ 256
#define HW_ (H_*W_)
#define L_ 1024
#define J_ 256
#define LC 128
#define NCH 8

// ws byte offsets
#define OFF_WFH  0ull
#define OFF_WFL  131072ull
#define OFF_WOF  262144ull
#define OFF_BIAS 327680ull
#define OFF_VWS  335872ull
#define OFF_MFR  (OFF_VWS + 33554432ull)

static __device__ __forceinline__ unsigned short f2bf(float x) {
    unsigned u = __builtin_bit_cast(unsigned, x);
    unsigned r = (u + 0x7FFFu + ((u >> 16) & 1u)) >> 16;
    return (unsigned short)r;
}
static __device__ __forceinline__ float bf2f(unsigned short h) {
    unsigned u = ((unsigned)h) << 16;
    return __builtin_bit_cast(float, u);
}
static __device__ __forceinline__ v4f mfma16(short8 a, short8 b, v4f c) {
    return __builtin_amdgcn_mfma_f32_16x16x32_bf16(a, b, c, 0, 0, 0);
}

union U8 { unsigned short u[8]; short8 v; };

// ---------------- prep: pack weights into MFMA A-fragment order ----------------
__global__ void prep_kernel(const float* __restrict__ w_v, const float* __restrict__ b_v,
                            const float* __restrict__ w1_1, const float* __restrict__ b1_1,
                            const float* __restrict__ w2_1, const float* __restrict__ b2_1,
                            const float* __restrict__ wout1,
                            const float* __restrict__ w1_2, const float* __restrict__ b1_2,
                            const float* __restrict__ w2_2, const float* __restrict__ b2_2,
                            const float* __restrict__ wout2,
                            char* __restrict__ wsb) {
    int tid = blockIdx.x * 256 + threadIdx.x;
    if (tid < 65536) {
        // proj weights: [s][omt 16][kc 4][lane 64][jj 8], rows o: w1(128), w2(64), wv-half(64)
        int jj = tid & 7, lane = (tid >> 3) & 63, kc = (tid >> 9) & 3;
        int omt = (tid >> 11) & 15, s = (tid >> 15) & 1;
        int o = omt * 16 + (lane & 15);
        int c = kc * 32 + ((lane >> 4) * 8) + jj;
        const float* w1 = s ? w1_2 : w1_1;
        const float* w2 = s ? w2_2 : w2_1;
        float v;
        if (o < 128)      v = w1[o * 128 + c];
        else if (o < 192) v = w2[(o - 128) * 128 + c];
        else              v = w_v[(o - 192) * 256 + s * 128 + c];
        unsigned short hi = f2bf(v);
        unsigned short lo = f2bf(v - bf2f(hi));
        ((unsigned short*)(wsb + OFF_WFH))[tid] = hi;
        ((unsigned short*)(wsb + OFF_WFL))[tid] = lo;
    } else if (tid < 98304) {
        int id = tid - 65536;
        int jj = id & 7, lane = (id >> 3) & 63, kc = (id >> 9) & 3;
        int om = (id >> 11) & 7, s = (id >> 14) & 1;
        int o = om * 16 + (lane & 15);
        int c = kc * 32 + ((lane >> 4) * 8) + jj;
        const float* wo = s ? wout2 : wout1;
        ((unsigned short*)(wsb + OFF_WOF))[id] = f2bf(wo[o * 128 + c]);
    } else if (tid < 98816) {
        int id = tid - 98304;
        int s = id >> 8, o = id & 255;
        const float* b1 = s ? b1_2 : b1_1;
        const float* b2 = s ? b2_2 : b2_1;
        float v;
        if (o < 128)      v = b1[o];
        else if (o < 192) v = b2[o - 128];
        else              v = b_v[o - 192];
        ((float*)(wsb + OFF_BIAS))[id] = v;
    }
}

// ---------------- fused per-j kernel ----------------
// waves 0-3: Y1 rows (c 0..127); waves 4-5: Y2 rows (k 0..63); waves 6-7: V logits
__global__ __launch_bounds__(512, 2) void fused_kernel(
    const float* __restrict__ x1, const float* __restrict__ x2,
    char* __restrict__ wsb) {
    // LDS layout (reused regions for epilogue)
    __shared__ __align__(16) char smem[151040];
    unsigned short* Xfh = (unsigned short*)&smem[0];       // B-frag order [ln8][kc4][lane][8]
    unsigned short* Xfl = (unsigned short*)&smem[32768];
    unsigned short* Y1b = (unsigned short*)&smem[65536];   // [128 c][136 l] bf16
    unsigned short* Y2b = (unsigned short*)&smem[100352];  // [64 k][136 l] bf16
    float*          LG  = (float*)&smem[117760];           // [128 l][65 k] fp32
    float*          UF  = (float*)&smem[0];                // [64 k][133 c] fp32 (epilogue)
    unsigned short* UH  = (unsigned short*)&smem[100352];  // [64 k][136 c] bf16 (epilogue)
    unsigned short* MB  = (unsigned short*)&smem[65536];   // [128 o][72 k] bf16 (epilogue)

    const unsigned short* wfh = (const unsigned short*)(wsb + OFF_WFH);
    const unsigned short* wfl = (const unsigned short*)(wsb + OFF_WFL);
    const unsigned short* wof = (const unsigned short*)(wsb + OFF_WOF);
    const float* biasws = (const float*)(wsb + OFF_BIAS);
    unsigned short* vws = (unsigned short*)(wsb + OFF_VWS);
    unsigned short* mfr = (unsigned short*)(wsb + OFF_MFR);

    const int t = threadIdx.x;
    const int lane = t & 63;
    const int w = __builtin_amdgcn_readfirstlane(t >> 6);
    const int j = blockIdx.x;
    const int b = j >> 6, q = j & 63, i0 = q >> 3, i2 = q & 7;
    const long imgbase = (long)b * C_ * HW_ + (long)(i0 * 32) * W_ + i2 * 32;

    const int lquad = lane >> 4;        // 0..3
    const int lmod = lane & 15;

    // W-hi fragments in registers: wreg[s][h][kc]
    short8 wreg[2][2][4];
#pragma unroll
    for (int s = 0; s < 2; s++)
#pragma unroll
        for (int h = 0; h < 2; h++)
#pragma unroll
            for (int kc = 0; kc < 4; kc++)
                wreg[s][h][kc] = *(const short8*)&wfh[(((s * 16 + (w * 2 + h)) * 4 + kc) * 64 + lane) * 8];
    // biases per lane (rows o = w*32 + h*16 + lquad*4 + r)
    float pb[2][2][4];
#pragma unroll
    for (int s = 0; s < 2; s++)
#pragma unroll
        for (int h = 0; h < 2; h++)
#pragma unroll
            for (int r = 0; r < 4; r++)
                pb[s][h][r] = biasws[s * 256 + w * 32 + h * 16 + lquad * 4 + r];

    v4f uacc[2][4];
#pragma unroll
    for (int s = 0; s < 2; s++)
#pragma unroll
        for (int kn = 0; kn < 4; kn++)
            uacc[s][kn] = (v4f){0.f, 0.f, 0.f, 0.f};

    // staging decode
    const int dl = t & 127, c8 = t >> 7;
    const int srow = dl >> 5, scol = dl & 31;
    const int sln = dl >> 4, slp = dl & 15;

    for (int lc = 0; lc < NCH; lc++) {
        v4f pacc[2][8];
#pragma unroll
        for (int s = 0; s < 2; s++) {
            const float* xp = s ? x2 : x1;
            // ---- stage X chunk (fp32 -> bf16 hi/lo, B-frag order) ----
#pragma unroll
            for (int p = 0; p < 4; p++) {
                int co = p * 4 + c8;
                U8 hv, lv;
#pragma unroll
                for (int jj = 0; jj < 8; jj++) {
                    int c = co * 8 + jj;
                    float v = xp[imgbase + (long)c * HW_ + (lc * 4 + srow) * W_ + scol];
                    unsigned short hh = f2bf(v);
                    hv.u[jj] = hh;
                    lv.u[jj] = f2bf(v - bf2f(hh));
                }
                int base = ((sln * 4 + (co >> 2)) * 64 + ((co & 3) * 16 + slp)) * 8;
                *(short8*)&Xfh[base] = hv.v;
                *(short8*)&Xfl[base] = lv.v;
            }
            __syncthreads();
            // ---- projection MFMAs (split-3: Whi*Xhi + Wlo*Xhi + Whi*Xlo) ----
            if (s == 0 || w < 6) {
#pragma unroll
                for (int h = 0; h < 2; h++)
#pragma unroll
                    for (int ln = 0; ln < 8; ln++)
                        pacc[h][ln] = (v4f){pb[s][h][0], pb[s][h][1], pb[s][h][2], pb[s][h][3]};
            }
#pragma unroll
            for (int kc = 0; kc < 4; kc++) {
                short8 wlo0 = *(const short8*)&wfl[(((s * 16 + (w * 2 + 0)) * 4 + kc) * 64 + lane) * 8];
                short8 wlo1 = *(const short8*)&wfl[(((s * 16 + (w * 2 + 1)) * 4 + kc) * 64 + lane) * 8];
#pragma unroll
                for (int ln = 0; ln < 8; ln++) {
                    short8 bh = *(const short8*)&Xfh[((ln * 4 + kc) * 64 + lane) * 8];
                    short8 bl = *(const short8*)&Xfl[((ln * 4 + kc) * 64 + lane) * 8];
                    pacc[0][ln] = mfma16(wreg[s][0][kc], bh, pacc[0][ln]);
                    pacc[0][ln] = mfma16(wlo0, bh, pacc[0][ln]);
                    pacc[0][ln] = mfma16(wreg[s][0][kc], bl, pacc[0][ln]);
                    pacc[1][ln] = mfma16(wreg[s][1][kc], bh, pacc[1][ln]);
                    pacc[1][ln] = mfma16(wlo1, bh, pacc[1][ln]);
                    pacc[1][ln] = mfma16(wreg[s][1][kc], bl, pacc[1][ln]);
                }
            }
            // ---- write Y / logits ----
            if (w < 4) {
#pragma unroll
                for (int h = 0; h < 2; h++)
#pragma unroll
                    for (int ln = 0; ln < 8; ln++)
#pragma unroll
                        for (int r = 0; r < 4; r++)
                            Y1b[(w * 32 + h * 16 + lquad * 4 + r) * 136 + ln * 16 + lmod] = f2bf(pacc[h][ln][r]);
            } else if (w < 6) {
#pragma unroll
                for (int h = 0; h < 2; h++)
#pragma unroll
                    for (int ln = 0; ln < 8; ln++)
#pragma unroll
                        for (int r = 0; r < 4; r++)
                            Y2b[((w - 4) * 32 + h * 16 + lquad * 4 + r) * 136 + ln * 16 + lmod] = f2bf(pacc[h][ln][r]);
            } else if (s == 1) {
#pragma unroll
                for (int h = 0; h < 2; h++)
#pragma unroll
                    for (int ln = 0; ln < 8; ln++)
#pragma unroll
                        for (int r = 0; r < 4; r++)
                            LG[(ln * 16 + lmod) * 65 + (w - 6) * 32 + h * 16 + lquad * 4 + r] = pacc[h][ln][r];
            }
            __syncthreads();
            // ---- U-MFMA: U_s += Y1 @ Y2^T over this l-chunk ----
#pragma unroll
            for (int kcl = 0; kcl < 4; kcl++) {
                short8 a = *(const short8*)&Y1b[(w * 16 + lmod) * 136 + kcl * 32 + lquad * 8];
#pragma unroll
                for (int kn = 0; kn < 4; kn++) {
                    short8 bb = *(const short8*)&Y2b[(kn * 16 + lmod) * 136 + kcl * 32 + lquad * 8];
                    uacc[s][kn] = mfma16(a, bb, uacc[s][kn]);
                }
            }
            if (s == 1) {
                // ---- softmax over k per column l ----
                if (t < 128) {
                    float* row = &LG[t * 65];
                    float mx = row[0];
#pragma unroll 8
                    for (int k = 1; k < 64; k++) mx = fmaxf(mx, row[k]);
                    float ssum = 0.f;
#pragma unroll 8
                    for (int k = 0; k < 64; k++) { float e = __expf(row[k] - mx); row[k] = e; ssum += e; }
                    float rs = 1.f / ssum;
#pragma unroll 8
                    for (int k = 0; k < 64; k++) row[k] *= rs;
                }
                __syncthreads();
                // ---- V store (bf16, [j][l][k]) ----
                {
                    int l2 = t >> 2, kq = (t & 3) * 16;
                    U8 o1, o2;
#pragma unroll
                    for (int i = 0; i < 8; i++) o1.u[i] = f2bf(LG[l2 * 65 + kq + i]);
#pragma unroll
                    for (int i = 0; i < 8; i++) o2.u[i] = f2bf(LG[l2 * 65 + kq + 8 + i]);
                    unsigned long long vb = ((unsigned long long)j * 1024 + lc * 128 + l2) * 64 + kq;
                    *(short8*)&vws[vb] = o1.v;
                    *(short8*)&vws[vb + 8] = o2.v;
                }
            }
        }
    }

    // ---------------- epilogue: l2norm(U) -> M = Wout @ Un -> mfrag ----------------
#pragma unroll
    for (int s = 0; s < 2; s++) {
        __syncthreads();
#pragma unroll
        for (int kn = 0; kn < 4; kn++)
#pragma unroll
            for (int r = 0; r < 4; r++)
                UF[(kn * 16 + lmod) * 133 + w * 16 + lquad * 4 + r] = uacc[s][kn][r];
        __syncthreads();
        if (t < 64) {
            const float* rp = &UF[t * 133];
            float ss = 0.f;
#pragma unroll 8
            for (int c = 0; c < 128; c++) ss += rp[c] * rp[c];
            UF[t * 133 + 128] = 1.f / (1e-6f + sqrtf(ss));
        }
        __syncthreads();
        {
            int kk = t >> 3, c0 = (t & 7) * 16;
            float rn = UF[kk * 133 + 128];
#pragma unroll
            for (int i = 0; i < 16; i++)
                UH[kk * 136 + c0 + i] = f2bf(UF[kk * 133 + c0 + i] * rn);
        }
        __syncthreads();
        v4f macc[4];
#pragma unroll
        for (int kn = 0; kn < 4; kn++) macc[kn] = (v4f){0.f, 0.f, 0.f, 0.f};
#pragma unroll
        for (int kc = 0; kc < 4; kc++) {
            short8 a = *(const short8*)&wof[(((s * 8 + w) * 4 + kc) * 64 + lane) * 8];
#pragma unroll
            for (int kn = 0; kn < 4; kn++) {
                short8 bb = *(const short8*)&UH[(kn * 16 + lmod) * 136 + kc * 32 + lquad * 8];
                macc[kn] = mfma16(a, bb, macc[kn]);
            }
        }
        __syncthreads();
#pragma unroll
        for (int kn = 0; kn < 4; kn++)
#pragma unroll
            for (int r = 0; r < 4; r++)
                MB[(w * 16 + lquad * 4 + r) * 72 + kn * 16 + lmod] = f2bf(macc[kn][r]);
        __syncthreads();
#pragma unroll
        for (int p = 0; p < 2; p++) {
            int id = p * 512 + t;
            int om = id >> 7, kc = (id >> 6) & 1, l2 = id & 63;
            short8 mv = *(const short8*)&MB[(om * 16 + (l2 & 15)) * 72 + kc * 32 + ((l2 >> 4) * 8)];
            *(short8*)&mfr[(((unsigned long long)j * 2 + s) * 1024 + id) * 8] = mv;
        }
    }
}

// ---------------- out = M @ V, scattered to image layout ----------------
__global__ __launch_bounds__(512, 2) void out_kernel(const char* __restrict__ wsb,
                                                     float* __restrict__ out) {
    const unsigned short* vws = (const unsigned short*)(wsb + OFF_VWS);
    const unsigned short* mfr = (const unsigned short*)(wsb + OFF_MFR);
    const int t = threadIdx.x;
    const int lane = t & 63;
    const int w = __builtin_amdgcn_readfirstlane(t >> 6);
    const int j = blockIdx.x;
    const int b = j >> 6, q = j & 63, i0 = q >> 3, i2 = q & 7;
    const long obase = (long)b * C_ * HW_ + (long)(i0 * 32) * W_ + i2 * 32;
    const int lquad = lane >> 4, lmod = lane & 15;

    short8 afr[2][2];
#pragma unroll
    for (int s = 0; s < 2; s++)
#pragma unroll
        for (int kc = 0; kc < 2; kc++)
            afr[s][kc] = *(const short8*)&mfr[(((unsigned long long)j * 2 + s) * 1024 + (w * 2 + kc) * 64 + lane) * 8];

    for (int ln = 0; ln < 64; ln++) {
        int l = ln * 16 + lmod;
        short8 b0 = *(const short8*)&vws[((unsigned long long)j * 1024 + l) * 64 + lquad * 8];
        short8 b1v = *(const short8*)&vws[((unsigned long long)j * 1024 + l) * 64 + 32 + lquad * 8];
        long base2 = obase + (long)(l >> 5) * W_ + (l & 31);
#pragma unroll
        for (int s = 0; s < 2; s++) {
            v4f acc = {0.f, 0.f, 0.f, 0.f};
            acc = mfma16(afr[s][0], b0, acc);
            acc = mfma16(afr[s][1], b1v, acc);
            long sb = base2 + (long)s * B_ * C_ * HW_;
#pragma unroll
            for (int r = 0; r < 4; r++) {
                int o = w * 16 + lquad * 4 + r;
                out[sb + (long)o * HW_] = acc[r];
            }
        }
    }
}

extern "C" void kernel_launch(void* const* d_in, const int* in_sizes, int n_in,
                              void* d_out, int out_size, void* d_ws, size_t ws_size,
                              hipStream_t stream) {
    (void)in_sizes; (void)n_in; (void)out_size; (void)ws_size;
    const float* x1    = (const float*)d_in[0];
    const float* x2    = (const float*)d_in[1];
    const float* w_v   = (const float*)d_in[2];
    const float* b_v   = (const float*)d_in[3];
    const float* w1_1  = (const float*)d_in[4];
    const float* b1_1  = (const float*)d_in[5];
    const float* w2_1  = (const float*)d_in[6];
    const float* b2_1  = (const float*)d_in[7];
    const float* wout1 = (const float*)d_in[8];
    const float* w1_2  = (const float*)d_in[9];
    const float* b1_2  = (const float*)d_in[10];
    const float* w2_2  = (const float*)d_in[11];
    const float* b2_2  = (const float*)d_in[12];
    const float* wout2 = (const float*)d_in[13];
    char* wsb  = (char*)d_ws;
    float* out = (float*)d_out;

    hipLaunchKernelGGL(prep_kernel, dim3(386), dim3(256), 0, stream,
                       w_v, b_v, w1_1, b1_1, w2_1, b2_1, wout1,
                       w1_2, b1_2, w2_2, b2_2, wout2, wsb);
    hipLaunchKernelGGL(fused_kernel, dim3(J_), dim3(512), 0, stream, x1, x2, wsb);
    hipLaunchKernelGGL(out_kernel, dim3(J_), dim3(512), 0, stream, wsb, out);
}